// Round 5
// baseline (475.076 us; speedup 1.0000x reference)
//
#include <hip/hip_runtime.h>
#include <math.h>

// Problem constants (from reference setup_inputs)
constexpr int  Bn  = 8;        // batch
constexpr int  Cin = 512;      // input channels
constexpr int  Nn  = 4096;     // H*W
constexpr int  Ck  = 256;      // key/query channels
constexpr int  Cv  = 256;      // value channels
constexpr int  Co  = 512;      // output channels

// d_out layout: [out | feat | feat | value]
constexpr size_t F1_OFF  = (size_t)Bn * Co * Nn;
constexpr size_t F2_OFF  = F1_OFF + (size_t)Bn * Ck * Nn;
constexpr size_t VAL_OFF = F2_OFF + (size_t)Bn * Ck * Nn;

typedef __attribute__((ext_vector_type(8)))  short  short8;   // 8 x bf16 frag
typedef __attribute__((ext_vector_type(16))) float  f32x16;   // 32x32 C/D frag
typedef __attribute__((ext_vector_type(8)))  ushort ushort8;

static __device__ __forceinline__ ushort f2bf(float f) {
    union { float f; unsigned u; } x; x.f = f;
    unsigned r = x.u + 0x7fffu + ((x.u >> 16) & 1u);   // RNE (no NaN inputs here)
    return (ushort)(r >> 16);
}

static __device__ __forceinline__ void gll16(const void* g, void* l) {
    __builtin_amdgcn_global_load_lds(
        (const __attribute__((address_space(1))) void*)g,
        (__attribute__((address_space(3))) void*)l, 16, 0, 0);
}

// ---------------------------------------------------------------------------
// Cast the three weight matrices to bf16 (all are 131072 elements).
// ---------------------------------------------------------------------------
__global__ __launch_bounds__(256) void cast_w(const float* __restrict__ a,
                                              const float* __restrict__ b,
                                              const float* __restrict__ c,
                                              ushort* __restrict__ da,
                                              ushort* __restrict__ db,
                                              ushort* __restrict__ dc)
{
    const int tid   = blockIdx.x * 256 + threadIdx.x;
    const int which = tid >> 14;                 // 16384 threads per matrix
    const int off   = (tid & 16383) * 8;
    const float* s = (which == 0) ? a : (which == 1) ? b : c;
    ushort*      d = (which == 0) ? da : (which == 1) ? db : dc;
    const float4 u = *(const float4*)(s + off);
    const float4 v = *(const float4*)(s + off + 4);
    ushort8 o;
    o[0] = f2bf(u.x); o[1] = f2bf(u.y); o[2] = f2bf(u.z); o[3] = f2bf(u.w);
    o[4] = f2bf(v.x); o[5] = f2bf(v.y); o[6] = f2bf(v.z); o[7] = f2bf(v.w);
    *(ushort8*)(d + off) = o;
}

// ---------------------------------------------------------------------------
// src fp32 [B][C][Nn] -> dst bf16 [B][Nn][C]  (LDS transpose, 64x64 tile)
// Round-5: vectorized — float4 reads (16B/lane), ushort8 writes (16B/lane).
// ---------------------------------------------------------------------------
__global__ __launch_bounds__(256) void transpose_c(const float* __restrict__ src,
                                                   ushort* __restrict__ dst, int C)
{
    const int b  = blockIdx.z;
    const int c0 = blockIdx.y * 64;
    const int n0 = blockIdx.x * 64;
    const int t  = threadIdx.x;
    __shared__ float T[64][65];
#pragma unroll
    for (int p = 0; p < 4; ++p) {                 // 1024 float4 loads
        const int flat = p * 256 + t;
        const int cc = flat >> 4, nn4 = (flat & 15) * 4;
        const float4 v = *(const float4*)(
            src + ((size_t)b * C + c0 + cc) * Nn + n0 + nn4);
        T[cc][nn4]     = v.x; T[cc][nn4 + 1] = v.y;
        T[cc][nn4 + 2] = v.z; T[cc][nn4 + 3] = v.w;
    }
    __syncthreads();
#pragma unroll
    for (int p = 0; p < 2; ++p) {                 // 512 ushort8 stores
        const int flat = p * 256 + t;
        const int nn = flat >> 3, cc0 = (flat & 7) * 8;
        ushort8 o;
#pragma unroll
        for (int i = 0; i < 8; ++i) o[i] = f2bf(T[cc0 + i][nn]);
        *(ushort8*)(dst + ((size_t)b * Nn + n0 + nn) * C + c0 + cc0) = o;
    }
}

// ---------------------------------------------------------------------------
// bf16 MFMA GEMM for the 1x1 convs (unchanged):
//   out[b][m][n] (+ optional bf16 copy) = sum_k Wb[m][k] * XT[b][n][k] + bias[m]
// ---------------------------------------------------------------------------
template <int K, bool DUAL>
__global__ __launch_bounds__(256) void gemm_bf(const ushort* __restrict__ XT,
                                               const ushort* __restrict__ Wb,
                                               const float*  __restrict__ bias,
                                               float* __restrict__ out,
                                               ushort* __restrict__ out_bf,
                                               int M)
{
    const int b  = blockIdx.z;
    const int m0 = blockIdx.y * 128;
    const int n0 = blockIdx.x * 128;
    const int t  = threadIdx.x;
    const int w  = t >> 6, L = t & 63;
    const int l31 = L & 31, hl = L >> 5;
    const int wm = (w >> 1) * 64, wn = (w & 1) * 64;

    __shared__ __align__(16) short As[128][72];   // [m][k]
    __shared__ __align__(16) short Bs[128][72];   // [n][k]

    const ushort* Xb = XT + (size_t)b * Nn * K;

    f32x16 acc[2][2];
#pragma unroll
    for (int a = 0; a < 2; ++a)
#pragma unroll
        for (int bb = 0; bb < 2; ++bb)
#pragma unroll
            for (int r = 0; r < 16; ++r) acc[a][bb][r] = 0.f;

    for (int k0 = 0; k0 < K; k0 += 64) {
        __syncthreads();
#pragma unroll
        for (int p = 0; p < 4; ++p) {            // stage 128x64 A and B tiles
            const int e   = p * 256 + t;
            const int row = e >> 3, ko = (e & 7) * 8;
            *(short8*)&As[row][ko] =
                *(const short8*)(Wb + (size_t)(m0 + row) * K + k0 + ko);
            *(short8*)&Bs[row][ko] =
                *(const short8*)(Xb + (size_t)(n0 + row) * K + k0 + ko);
        }
        __syncthreads();
#pragma unroll
        for (int kc = 0; kc < 4; ++kc) {
            short8 Af[2], Bf[2];
#pragma unroll
            for (int a = 0; a < 2; ++a)
                Af[a] = *(const short8*)&As[wm + a * 32 + l31][kc * 16 + hl * 8];
#pragma unroll
            for (int bb = 0; bb < 2; ++bb)
                Bf[bb] = *(const short8*)&Bs[wn + bb * 32 + l31][kc * 16 + hl * 8];
#pragma unroll
            for (int a = 0; a < 2; ++a)
#pragma unroll
                for (int bb = 0; bb < 2; ++bb)
                    acc[a][bb] = __builtin_amdgcn_mfma_f32_32x32x16_bf16(
                        Af[a], Bf[bb], acc[a][bb], 0, 0, 0);
        }
    }

    // epilogue: D row=(r&3)+8*(r>>2)+4*hl, col=l31
#pragma unroll
    for (int a = 0; a < 2; ++a)
#pragma unroll
        for (int r = 0; r < 16; ++r) {
            const int row = (r & 3) + 8 * (r >> 2) + 4 * hl;
            const int o   = m0 + wm + a * 32 + row;
            const float bv = bias[o];
            const size_t base = ((size_t)b * M + o) * Nn + n0 + wn + l31;
#pragma unroll
            for (int bb = 0; bb < 2; ++bb) {
                const float vv = acc[a][bb][r] + bv;
                out[base + bb * 32] = vv;
                if (DUAL) out_bf[base + bb * 32] = f2bf(vv);
            }
        }
}

// ---------------------------------------------------------------------------
// BN training stats (unchanged)
// ---------------------------------------------------------------------------
__global__ __launch_bounds__(256) void bn_stats(const float* __restrict__ qk,
                                                const float* __restrict__ gamma,
                                                const float* __restrict__ beta,
                                                float* __restrict__ ss)
{
    const int o = blockIdx.x;
    const int t = threadIdx.x;
    float s = 0.f, sq = 0.f;
    for (int b = 0; b < Bn; ++b) {
        const float* p = qk + ((size_t)b * Ck + o) * Nn;
        for (int n = t * 4; n < Nn; n += 1024) {
            const float4 v = *(const float4*)(p + n);
            s  += v.x + v.y + v.z + v.w;
            sq += v.x * v.x + v.y * v.y + v.z * v.z + v.w * v.w;
        }
    }
    __shared__ float rs[256], rq[256];
    rs[t] = s; rq[t] = sq;
    __syncthreads();
    for (int off = 128; off > 0; off >>= 1) {
        if (t < off) { rs[t] += rs[t + off]; rq[t] += rq[t + off]; }
        __syncthreads();
    }
    if (t == 0) {
        const float cnt  = (float)(Bn * Nn);
        const float mean = rs[0] / cnt;
        const float var  = rq[0] / cnt - mean * mean;
        const float inv  = rsqrtf(var + 1e-5f);
        const float sc   = gamma[o] * inv;
        ss[o]       = sc;
        ss[256 + o] = beta[o] - mean * sc;
    }
}

// ---------------------------------------------------------------------------
// feat = relu(qk * scale + shift) -> both fp32 feat slots (unchanged)
// ---------------------------------------------------------------------------
__global__ __launch_bounds__(256) void bn_relu(const float* __restrict__ qk,
                                               const float* __restrict__ ss,
                                               float* __restrict__ f1,
                                               float* __restrict__ f2)
{
    const size_t tid = (size_t)blockIdx.x * 256 + threadIdx.x;
    const size_t idx = tid * 4;
    const int o = (int)((idx >> 12) & 255);
    const float sc = ss[o], sh = ss[256 + o];
    const float4 v = *(const float4*)(qk + idx);
    float4 r;
    r.x = fmaxf(v.x * sc + sh, 0.f);
    r.y = fmaxf(v.y * sc + sh, 0.f);
    r.z = fmaxf(v.z * sc + sh, 0.f);
    r.w = fmaxf(v.w * sc + sh, 0.f);
    *(float4*)(f1 + idx) = r;
    *(float4*)(f2 + idx) = r;
}

// ---------------------------------------------------------------------------
// bf16 MFMA flash attention, no-max softmax (scores >= 0, <= ~33).
//   featT [B][Nn][Ck] bf16, valB [B][Cv][Nn] bf16, ctx OUT bf16 [B][Nn][Cv]
//
// Round-5 restructure: 1 barrier per tile, QK(s) // PV(s-1) dual-stream.
//   iter s body:
//     stage K(s+1)->K[cur^1], V(s)->V[cur]      (8 gll16, fly all iter)
//     QK(s)  <- K[cur]        (16 ds_read + 16 MFMA)
//     PV(s-1)<- P[cur^1], V[cur^1]  (2+16 ds_read + 16 MFMA, independent!)
//     exp/pack(s) (VALU, hides under PV) ; P-write(s) -> P[cur]
//     s_waitcnt vmcnt(0) lgkmcnt(0)   // MY glls + ds ops drained
//     s_barrier                        // => ALL waves' staged data visible
//   Own 2 P-frags stay in registers across the iter (2 of 4 PV A-frags
//   free); partner's 2 read from LDS. P double-buffered (write cur, read
//   cur^1). Buffer safety: all same-iter accesses hit disjoint buffers;
//   vmcnt(0) BEFORE the barrier closes the cross-wave gll16 hazard.
// Kept: swapped QK^T + in-reg P (permlane32_swap), gll16 + per-row rotation
// (verified), batch->XCD grid, setprio, cv-split PV (Oacc[4], no spill).
// LDS: K 2x32K + V 2x32K + P 2x16K = 163840 B (AITER attn precedent).
// ---------------------------------------------------------------------------
constexpr int LDS_BYTES = 163840;

__global__ __launch_bounds__(512) void attn_mfma(const ushort* __restrict__ featT,
                                                 const ushort* __restrict__ valB,
                                                 ushort* __restrict__ ctx)
{
    extern __shared__ __align__(16) char lds[];
    char* ldsK = lds;              // [buf][64 rows][512 B]  (rotated image)
    char* ldsV = lds + 65536;      // [buf][256 rows][128 B] (rotated image)
    char* ldsP = lds + 131072;     // [buf][ig 4][jb 4][hl 2][32 lanes x 16 B]

    const int b   = blockIdx.x;                  // batch -> XCD affinity
    const int i0  = blockIdx.y * 128;
    const int t   = threadIdx.x;
    const int w   = t >> 6;
    const int L   = t & 63;
    const int l31 = L & 31, hl = L >> 5;
    const int ig  = w >> 1;                      // i-group 0..3 (32 rows each)
    const int ch  = w & 1;                       // j-half (QK) / cv-half (PV)
    const int jsel = ch * 32;

    // read-side rotation bases (verified rounds 3-4)
    const int rbK  = hl * 16 + (((jsel + l31) << 4) & 511);
    const int rotV = (l31 << 4) & 127;

    const ushort* F = featT + (size_t)b * Nn * Ck;
    const ushort* V = valB  + (size_t)b * Cv * Nn;
    const char*   Vg = (const char*)V;

    constexpr float CEXP = 0.09016844005556021f;  // log2(e)/16
    constexpr int NT = Nn / 64;                   // 64 j-tiles

#define STAGE_K(J0, BUF) do {                                                  \
        const char* Kg_ = (const char*)(F + (size_t)(J0) * Ck);                \
        char* Kd_ = ldsK + (BUF) * 32768;                                      \
        _Pragma("unroll")                                                      \
        for (int p_ = 0; p_ < 4; ++p_) {                                       \
            const int c_ = w * 4 + p_;                                         \
            const int o_ = c_ * 1024 + L * 16;                                 \
            const int rK_ = o_ >> 9;                                           \
            gll16(Kg_ + rK_ * 512 + ((o_ - rK_ * 16) & 511), Kd_ + c_ * 1024); \
        }                                                                      \
    } while (0)

#define STAGE_V(J0, BUF) do {                                                  \
        char* Vd_ = ldsV + (BUF) * 32768;                                      \
        _Pragma("unroll")                                                      \
        for (int p_ = 0; p_ < 4; ++p_) {                                       \
            const int c_ = w * 4 + p_;                                         \
            const int o_ = c_ * 1024 + L * 16;                                 \
            const int rV_ = o_ >> 7;                                           \
            gll16(Vg + (size_t)rV_ * (Nn * 2) + (size_t)(J0) * 2               \
                     + ((o_ - rV_ * 16) & 127), Vd_ + c_ * 1024);              \
        }                                                                      \
    } while (0)

    // prologue: K(0) staged; Q fragments; drain + align all waves
    STAGE_K(0, 0);
    short8 Qf[16];
    {
        const ushort* qp = F + ((size_t)(i0 + ig * 32 + l31)) * Ck + hl * 8;
#pragma unroll
        for (int kc = 0; kc < 16; ++kc)
            Qf[kc] = *(const short8*)(qp + kc * 16);
    }
    asm volatile("s_waitcnt vmcnt(0)" ::: "memory");
    __builtin_amdgcn_s_barrier();

    f32x16 Oacc[4];
#pragma unroll
    for (int c = 0; c < 4; ++c)
#pragma unroll
        for (int r = 0; r < 16; ++r) Oacc[c][r] = 0.f;
    float lsum = 0.f;
    short8 PfA{}, PfB{};                          // own P(s-1) frags

    int cur = 0;
    for (int s = 0; s < NT; ++s) {
        // stage K(s+1) and V(s) — consumed next iteration
        const int jn = (s + 1 < NT ? s + 1 : NT - 1) * 64;
        STAGE_K(jn, cur ^ 1);
        STAGE_V((size_t)s * 64, cur);

        // ---- QK(s): S^T[j][i] from K[cur] ----
        const char* Kr = ldsK + cur * 32768 + (jsel + l31) * 512;
        f32x16 Sa, Sb;
#pragma unroll
        for (int r = 0; r < 16; ++r) { Sa[r] = 0.f; Sb[r] = 0.f; }
        __builtin_amdgcn_s_setprio(1);
#pragma unroll
        for (int kc = 0; kc < 8; ++kc) {
            const short8 K0 = *(const short8*)(Kr + ((kc * 64      + rbK) & 511));
            const short8 K1 = *(const short8*)(Kr + ((kc * 64 + 32 + rbK) & 511));
            Sa = __builtin_amdgcn_mfma_f32_32x32x16_bf16(K0, Qf[2 * kc],     Sa, 0, 0, 0);
            Sb = __builtin_amdgcn_mfma_f32_32x32x16_bf16(K1, Qf[2 * kc + 1], Sb, 0, 0, 0);
        }
        __builtin_amdgcn_s_setprio(0);

        // ---- PV(s-1): P[cur^1] (+ own regs) x V[cur^1] ----
        if (s > 0) {
            const char* Vr2 = ldsV + (cur ^ 1) * 32768 + (ch * 128 + l31) * 128;
            const char* Pr  = ldsP + (cur ^ 1) * 16384
                              + ((ig * 4 + (ch ^ 1) * 2) * 2 + hl) * 512 + l31 * 16;
            const short8 Po0 = *(const short8*)(Pr);
            const short8 Po1 = *(const short8*)(Pr + 1024);
            __builtin_amdgcn_s_setprio(1);
#pragma unroll
            for (int g = 0; g < 2; ++g) {          // own j-half (regs)
                const short8 Pa = g ? PfB : PfA;
                const int jbyte = (ch * 2 + g) * 32 + hl * 16;
#pragma unroll
                for (int cvt = 0; cvt < 4; ++cvt) {
                    const short8 Vf = *(const short8*)(Vr2 + cvt * 4096
                                         + ((jbyte + rotV) & 127));
                    Oacc[cvt] = __builtin_amdgcn_mfma_f32_32x32x16_bf16(
                        Pa, Vf, Oacc[cvt], 0, 0, 0);
                }
            }
#pragma unroll
            for (int g = 0; g < 2; ++g) {          // partner j-half (LDS)
                const short8 Pa = g ? Po1 : Po0;
                const int jbyte = ((ch ^ 1) * 2 + g) * 32 + hl * 16;
#pragma unroll
                for (int cvt = 0; cvt < 4; ++cvt) {
                    const short8 Vf = *(const short8*)(Vr2 + cvt * 4096
                                         + ((jbyte + rotV) & 127));
                    Oacc[cvt] = __builtin_amdgcn_mfma_f32_32x32x16_bf16(
                        Pa, Vf, Oacc[cvt], 0, 0, 0);
                }
            }
            __builtin_amdgcn_s_setprio(0);
        }

        // ---- exp + bf16 round + row-sum + pack (hides under PV) ----
        unsigned pw[8];
#pragma unroll
        for (int r2 = 0; r2 < 8; ++r2) {
            const float p0 = exp2f((Sa[2 * r2]     + Sb[2 * r2])     * CEXP);
            const float p1 = exp2f((Sa[2 * r2 + 1] + Sb[2 * r2 + 1]) * CEXP);
            const unsigned u0 = (unsigned)f2bf(p0);
            const unsigned u1 = (unsigned)f2bf(p1);
            lsum += __uint_as_float(u0 << 16) + __uint_as_float(u1 << 16);
            pw[r2] = u0 | (u1 << 16);
        }
        {
            char* Pw = ldsP + cur * 16384
                       + ((ig * 4 + ch * 2) * 2 + hl) * 512 + l31 * 16;
            short8 nf[2];
#pragma unroll
            for (int g = 0; g < 2; ++g) {
                auto s02 = __builtin_amdgcn_permlane32_swap(pw[4 * g + 0], pw[4 * g + 2],
                                                            false, false);
                auto s13 = __builtin_amdgcn_permlane32_swap(pw[4 * g + 1], pw[4 * g + 3],
                                                            false, false);
                union { unsigned u[4]; short8 s; } pu;
                pu.u[0] = s02[0]; pu.u[1] = s13[0]; pu.u[2] = s02[1]; pu.u[3] = s13[1];
                nf[g] = pu.s;
                *(short8*)(Pw + g * 1024) = pu.s;
            }
            PfA = nf[0]; PfB = nf[1];
        }

        // drain MY glls + ds ops, then align: everyone's staging visible
        asm volatile("s_waitcnt vmcnt(0) lgkmcnt(0)" ::: "memory");
        __builtin_amdgcn_s_barrier();
        cur ^= 1;
    }
#undef STAGE_K
#undef STAGE_V

    // ---- epilogue PV(NT-1): P[cur^1], V[cur^1] ----
    {
        const char* Vr2 = ldsV + (cur ^ 1) * 32768 + (ch * 128 + l31) * 128;
        const char* Pr  = ldsP + (cur ^ 1) * 16384
                          + ((ig * 4 + (ch ^ 1) * 2) * 2 + hl) * 512 + l31 * 16;
        const short8 Po0 = *(const short8*)(Pr);
        const short8 Po1 = *(const short8*)(Pr + 1024);
#pragma unroll
        for (int g = 0; g < 2; ++g) {
            const short8 Pa = g ? PfB : PfA;
            const int jbyte = (ch * 2 + g) * 32 + hl * 16;
#pragma unroll
            for (int cvt = 0; cvt < 4; ++cvt) {
                const short8 Vf = *(const short8*)(Vr2 + cvt * 4096
                                     + ((jbyte + rotV) & 127));
                Oacc[cvt] = __builtin_amdgcn_mfma_f32_32x32x16_bf16(
                    Pa, Vf, Oacc[cvt], 0, 0, 0);
            }
        }
#pragma unroll
        for (int g = 0; g < 2; ++g) {
            const short8 Pa = g ? Po1 : Po0;
            const int jbyte = ((ch ^ 1) * 2 + g) * 32 + hl * 16;
#pragma unroll
            for (int cvt = 0; cvt < 4; ++cvt) {
                const short8 Vf = *(const short8*)(Vr2 + cvt * 4096
                                     + ((jbyte + rotV) & 127));
                Oacc[cvt] = __builtin_amdgcn_mfma_f32_32x32x16_bf16(
                    Pa, Vf, Oacc[cvt], 0, 0, 0);
            }
        }
    }

    // ---- l merge (hl in-reg, ch via LDS; Lr aliases dead P buf 0) ----
    {
        unsigned a = __float_as_uint(lsum), bcopy = a;
        auto sw = __builtin_amdgcn_permlane32_swap(a, bcopy, false, false);
        lsum = __uint_as_float(sw[0]) + __uint_as_float(sw[1]);
    }
    float* Lr = (float*)ldsP;          // P buf0: last read was PV(NT-2)
    Lr[(ig * 2 + ch) * 32 + l31] = lsum;
    asm volatile("s_waitcnt lgkmcnt(0)" ::: "memory");
    __builtin_amdgcn_s_barrier();

    ushort* Cb = ctx + ((size_t)b * Nn + i0 + ig * 32) * Cv + ch * 128;
#pragma unroll
    for (int r = 0; r < 16; ++r) {
        const int row = (r & 3) + 8 * (r >> 2) + 4 * hl;
        const float lt = Lr[(ig * 2) * 32 + row] + Lr[(ig * 2 + 1) * 32 + row];
        const float linv = 1.f / lt;
        ushort* cp = Cb + (size_t)row * Cv + l31;
#pragma unroll
        for (int c4 = 0; c4 < 4; ++c4)
            cp[c4 * 32] = f2bf(Oacc[c4][r] * linv);
    }
}

// ---------------------------------------------------------------------------
extern "C" void kernel_launch(void* const* d_in, const int* in_sizes, int n_in,
                              void* d_out, int out_size, void* d_ws, size_t ws_size,
                              hipStream_t stream)
{
    const float* x     = (const float*)d_in[0];
    const float* Wk    = (const float*)d_in[1];
    const float* bk    = (const float*)d_in[2];
    const float* gamma = (const float*)d_in[3];
    const float* beta  = (const float*)d_in[4];
    const float* Wv    = (const float*)d_in[5];
    const float* bv    = (const float*)d_in[6];
    const float* Ww    = (const float*)d_in[7];
    const float* bw    = (const float*)d_in[8];

    float* out = (float*)d_out;
    float* f1  = out + F1_OFF;
    float* f2  = out + F2_OFF;
    float* val = out + VAL_OFF;

    // workspace packing (51.1 MB), with aliasing over dead xT:
    //   xT    : [0 .. 16,777,216) ushorts   live steps 2-4
    //   featT : alias xT[0 .. 8,388,608)    live steps 7-8
    //   ctxb  : alias xT[8,388,608 .. )     live steps 8-9
    ushort* xT    = (ushort*)d_ws;                       // [B][Nn][Cin]
    ushort* featT = xT;                                  // [B][Nn][Ck]
    ushort* ctxb  = xT + (size_t)8388608;                // [B][Nn][Cv]
    ushort* valB  = xT + (size_t)16777216;               // [B][Cv][Nn]
    ushort* Wkb   = valB + (size_t)8388608;
    ushort* Wvb   = Wkb + 131072;
    ushort* Wwb   = Wvb + 131072;
    float*  ss    = (float*)(Wwb + 131072);              // 512 floats

    // one-time: allow 160 KB dynamic LDS for the attention kernel
    static bool attn_attr_set = false;
    if (!attn_attr_set) {
        (void)hipFuncSetAttribute((const void*)attn_mfma,
                                  hipFuncAttributeMaxDynamicSharedMemorySize,
                                  LDS_BYTES);
        attn_attr_set = true;
    }

    // 1) weights -> bf16
    cast_w<<<192, 256, 0, stream>>>(Wk, Wv, Ww, Wkb, Wvb, Wwb);
    // 2) x -> xT bf16 [B][Nn][Cin]
    transpose_c<<<dim3(Nn / 64, Cin / 64, Bn), 256, 0, stream>>>(x, xT, Cin);
    // 3) qk = Wk*x + bk (fp32, into feat1 slot)
    gemm_bf<512, false><<<dim3(Nn / 128, Ck / 128, Bn), 256, 0, stream>>>(
        xT, Wkb, bk, f1, nullptr, Ck);
    // 4) value = Wv*x + bv (fp32 output + bf16 copy for attention)
    gemm_bf<512, true><<<dim3(Nn / 128, Cv / 128, Bn), 256, 0, stream>>>(
        xT, Wvb, bv, val, valB, Cv);
    // 5) BN stats
    bn_stats<<<Ck, 256, 0, stream>>>(f1, gamma, beta, ss);
    // 6) feat = relu(norm(qk)) -> f1 (in place) and f2
    bn_relu<<<(Bn * Ck * Nn) / (256 * 4), 256, 0, stream>>>(f1, ss, f1, f2);
    // 7) feat -> featT bf16 [B][Nn][Ck]   (xT dead, aliased)
    transpose_c<<<dim3(Nn / 64, Ck / 64, Bn), 256, 0, stream>>>(f1, featT, Ck);
    // 8) flash attention -> ctx bf16 [B][Nn][Cv]
    attn_mfma<<<dim3(Bn, Nn / 128), 512, LDS_BYTES, stream>>>(featT, valB, ctxb);
    // 9) out = Ww*ctx + bw
    gemm_bf<256, false><<<dim3(Nn / 128, Co / 128, Bn), 256, 0, stream>>>(
        ctxb, Wwb, bw, out, nullptr, Co);
}

// Round 6
// 438.112 us; speedup vs baseline: 1.0844x; 1.0844x over previous
//
#include <hip/hip_runtime.h>
#include <math.h>

// Problem constants (from reference setup_inputs)
constexpr int  Bn  = 8;        // batch
constexpr int  Cin = 512;      // input channels
constexpr int  Nn  = 4096;     // H*W
constexpr int  Ck  = 256;      // key/query channels
constexpr int  Cv  = 256;      // value channels
constexpr int  Co  = 512;      // output channels

// d_out layout: [out | feat | feat | value]
constexpr size_t F1_OFF  = (size_t)Bn * Co * Nn;
constexpr size_t F2_OFF  = F1_OFF + (size_t)Bn * Ck * Nn;
constexpr size_t VAL_OFF = F2_OFF + (size_t)Bn * Ck * Nn;

typedef __attribute__((ext_vector_type(8)))  short  short8;   // 8 x bf16 frag
typedef __attribute__((ext_vector_type(16))) float  f32x16;   // 32x32 C/D frag
typedef __attribute__((ext_vector_type(8)))  ushort ushort8;

static __device__ __forceinline__ ushort f2bf(float f) {
    union { float f; unsigned u; } x; x.f = f;
    unsigned r = x.u + 0x7fffu + ((x.u >> 16) & 1u);   // RNE (no NaN inputs here)
    return (ushort)(r >> 16);
}

static __device__ __forceinline__ void gll16(const void* g, void* l) {
    __builtin_amdgcn_global_load_lds(
        (const __attribute__((address_space(1))) void*)g,
        (__attribute__((address_space(3))) void*)l, 16, 0, 0);
}

// ---------------------------------------------------------------------------
// Cast the three weight matrices to bf16 (all are 131072 elements).
// ---------------------------------------------------------------------------
__global__ __launch_bounds__(256) void cast_w(const float* __restrict__ a,
                                              const float* __restrict__ b,
                                              const float* __restrict__ c,
                                              ushort* __restrict__ da,
                                              ushort* __restrict__ db,
                                              ushort* __restrict__ dc)
{
    const int tid   = blockIdx.x * 256 + threadIdx.x;
    const int which = tid >> 14;                 // 16384 threads per matrix
    const int off   = (tid & 16383) * 8;
    const float* s = (which == 0) ? a : (which == 1) ? b : c;
    ushort*      d = (which == 0) ? da : (which == 1) ? db : dc;
    const float4 u = *(const float4*)(s + off);
    const float4 v = *(const float4*)(s + off + 4);
    ushort8 o;
    o[0] = f2bf(u.x); o[1] = f2bf(u.y); o[2] = f2bf(u.z); o[3] = f2bf(u.w);
    o[4] = f2bf(v.x); o[5] = f2bf(v.y); o[6] = f2bf(v.z); o[7] = f2bf(v.w);
    *(ushort8*)(d + off) = o;
}

// ---------------------------------------------------------------------------
// src fp32 [B][C][Nn] -> dst bf16 [B][Nn][C]  (LDS transpose, 64x64 tile)
// float4 reads (16B/lane), ushort8 writes (16B/lane).
// ---------------------------------------------------------------------------
__global__ __launch_bounds__(256) void transpose_c(const float* __restrict__ src,
                                                   ushort* __restrict__ dst, int C)
{
    const int b  = blockIdx.z;
    const int c0 = blockIdx.y * 64;
    const int n0 = blockIdx.x * 64;
    const int t  = threadIdx.x;
    __shared__ float T[64][65];
#pragma unroll
    for (int p = 0; p < 4; ++p) {                 // 1024 float4 loads
        const int flat = p * 256 + t;
        const int cc = flat >> 4, nn4 = (flat & 15) * 4;
        const float4 v = *(const float4*)(
            src + ((size_t)b * C + c0 + cc) * Nn + n0 + nn4);
        T[cc][nn4]     = v.x; T[cc][nn4 + 1] = v.y;
        T[cc][nn4 + 2] = v.z; T[cc][nn4 + 3] = v.w;
    }
    __syncthreads();
#pragma unroll
    for (int p = 0; p < 2; ++p) {                 // 512 ushort8 stores
        const int flat = p * 256 + t;
        const int nn = flat >> 3, cc0 = (flat & 7) * 8;
        ushort8 o;
#pragma unroll
        for (int i = 0; i < 8; ++i) o[i] = f2bf(T[cc0 + i][nn]);
        *(ushort8*)(dst + ((size_t)b * Nn + n0 + nn) * C + c0 + cc0) = o;
    }
}

// ---------------------------------------------------------------------------
// Fused QK/V GEMM: stages the shared xT B-tile ONCE, runs both Wk and Wv.
//   qk[b][m][n]  = sum_k Wk[m][k] * XT[b][n][k] + bk[m]        (fp32)
//   val[b][m][n] = sum_k Wv[m][k] * XT[b][n][k] + bv[m]        (fp32 + bf16)
// Tile 128m x 128n, 4 waves, 8 MFMA / 6 ds_read_b128 per kc step.
// Halves xT read traffic vs two separate GEMMs.
// ---------------------------------------------------------------------------
__global__ __launch_bounds__(256) void gemm_qv(const ushort* __restrict__ XT,
                                               const ushort* __restrict__ Wkb,
                                               const ushort* __restrict__ Wvb,
                                               const float*  __restrict__ bk,
                                               const float*  __restrict__ bv,
                                               float* __restrict__ qk,
                                               float* __restrict__ val,
                                               ushort* __restrict__ valB)
{
    const int b  = blockIdx.z;
    const int m0 = blockIdx.y * 128;
    const int n0 = blockIdx.x * 128;
    const int t  = threadIdx.x;
    const int w  = t >> 6, L = t & 63;
    const int l31 = L & 31, hl = L >> 5;
    const int wm = (w >> 1) * 64, wn = (w & 1) * 64;

    __shared__ __align__(16) short AsK[128][72];
    __shared__ __align__(16) short AsV[128][72];
    __shared__ __align__(16) short Bs[128][72];

    const ushort* Xb = XT + (size_t)b * Nn * Cin;

    f32x16 accK[2][2], accV[2][2];
#pragma unroll
    for (int a = 0; a < 2; ++a)
#pragma unroll
        for (int bb = 0; bb < 2; ++bb)
#pragma unroll
            for (int r = 0; r < 16; ++r) { accK[a][bb][r] = 0.f; accV[a][bb][r] = 0.f; }

    for (int k0 = 0; k0 < Cin; k0 += 64) {
        __syncthreads();
#pragma unroll
        for (int p = 0; p < 4; ++p) {            // stage Wk, Wv, xT tiles
            const int e   = p * 256 + t;
            const int row = e >> 3, ko = (e & 7) * 8;
            *(short8*)&AsK[row][ko] =
                *(const short8*)(Wkb + (size_t)(m0 + row) * Cin + k0 + ko);
            *(short8*)&AsV[row][ko] =
                *(const short8*)(Wvb + (size_t)(m0 + row) * Cin + k0 + ko);
            *(short8*)&Bs[row][ko] =
                *(const short8*)(Xb + (size_t)(n0 + row) * Cin + k0 + ko);
        }
        __syncthreads();
#pragma unroll
        for (int kc = 0; kc < 4; ++kc) {
            short8 Ak[2], Av[2], Bf[2];
#pragma unroll
            for (int a = 0; a < 2; ++a) {
                Ak[a] = *(const short8*)&AsK[wm + a * 32 + l31][kc * 16 + hl * 8];
                Av[a] = *(const short8*)&AsV[wm + a * 32 + l31][kc * 16 + hl * 8];
            }
#pragma unroll
            for (int bb = 0; bb < 2; ++bb)
                Bf[bb] = *(const short8*)&Bs[wn + bb * 32 + l31][kc * 16 + hl * 8];
#pragma unroll
            for (int a = 0; a < 2; ++a)
#pragma unroll
                for (int bb = 0; bb < 2; ++bb) {
                    accK[a][bb] = __builtin_amdgcn_mfma_f32_32x32x16_bf16(
                        Ak[a], Bf[bb], accK[a][bb], 0, 0, 0);
                    accV[a][bb] = __builtin_amdgcn_mfma_f32_32x32x16_bf16(
                        Av[a], Bf[bb], accV[a][bb], 0, 0, 0);
                }
        }
    }

    // epilogue: D row=(r&3)+8*(r>>2)+4*hl, col=l31
#pragma unroll
    for (int a = 0; a < 2; ++a)
#pragma unroll
        for (int r = 0; r < 16; ++r) {
            const int row = (r & 3) + 8 * (r >> 2) + 4 * hl;
            const int o   = m0 + wm + a * 32 + row;
            const float bkv = bk[o], bvv = bv[o];
            const size_t base = ((size_t)b * Ck + o) * Nn + n0 + wn + l31;
#pragma unroll
            for (int bb = 0; bb < 2; ++bb) {
                qk[base + bb * 32] = accK[a][bb][r] + bkv;
                const float vv = accV[a][bb][r] + bvv;
                val[base + bb * 32]  = vv;
                valB[base + bb * 32] = f2bf(vv);
            }
        }
}

// ---------------------------------------------------------------------------
// BN training stats (unchanged)
// ---------------------------------------------------------------------------
__global__ __launch_bounds__(256) void bn_stats(const float* __restrict__ qk,
                                                const float* __restrict__ gamma,
                                                const float* __restrict__ beta,
                                                float* __restrict__ ss)
{
    const int o = blockIdx.x;
    const int t = threadIdx.x;
    float s = 0.f, sq = 0.f;
    for (int b = 0; b < Bn; ++b) {
        const float* p = qk + ((size_t)b * Ck + o) * Nn;
        for (int n = t * 4; n < Nn; n += 1024) {
            const float4 v = *(const float4*)(p + n);
            s  += v.x + v.y + v.z + v.w;
            sq += v.x * v.x + v.y * v.y + v.z * v.z + v.w * v.w;
        }
    }
    __shared__ float rs[256], rq[256];
    rs[t] = s; rq[t] = sq;
    __syncthreads();
    for (int off = 128; off > 0; off >>= 1) {
        if (t < off) { rs[t] += rs[t + off]; rq[t] += rq[t + off]; }
        __syncthreads();
    }
    if (t == 0) {
        const float cnt  = (float)(Bn * Nn);
        const float mean = rs[0] / cnt;
        const float var  = rq[0] / cnt - mean * mean;
        const float inv  = rsqrtf(var + 1e-5f);
        const float sc   = gamma[o] * inv;
        ss[o]       = sc;
        ss[256 + o] = beta[o] - mean * sc;
    }
}

// ---------------------------------------------------------------------------
// Fused BN-apply + ReLU + channel transpose:
//   reads qk (f1 slot), writes f1/f2 fp32 (coalesced, same layout) AND
//   featT bf16 [B][Nn][Ck] via LDS transpose. Saves one full feat pass.
// ---------------------------------------------------------------------------
__global__ __launch_bounds__(256) void bn_relu_t(const float* __restrict__ qk,
                                                 const float* __restrict__ ss,
                                                 float* __restrict__ f1,
                                                 float* __restrict__ f2,
                                                 ushort* __restrict__ featT)
{
    const int b  = blockIdx.z;
    const int c0 = blockIdx.y * 64;
    const int n0 = blockIdx.x * 64;
    const int t  = threadIdx.x;
    __shared__ float T[64][65];
#pragma unroll
    for (int p = 0; p < 4; ++p) {                 // float4 load + BN + relu
        const int flat = p * 256 + t;
        const int cc = flat >> 4, nn4 = (flat & 15) * 4;
        const size_t gidx = ((size_t)b * Ck + c0 + cc) * Nn + n0 + nn4;
        const float sc = ss[c0 + cc], sh = ss[256 + c0 + cc];
        const float4 v = *(const float4*)(qk + gidx);
        float4 r;
        r.x = fmaxf(v.x * sc + sh, 0.f);
        r.y = fmaxf(v.y * sc + sh, 0.f);
        r.z = fmaxf(v.z * sc + sh, 0.f);
        r.w = fmaxf(v.w * sc + sh, 0.f);
        *(float4*)(f1 + gidx) = r;
        *(float4*)(f2 + gidx) = r;
        T[cc][nn4]     = r.x; T[cc][nn4 + 1] = r.y;
        T[cc][nn4 + 2] = r.z; T[cc][nn4 + 3] = r.w;
    }
    __syncthreads();
#pragma unroll
    for (int p = 0; p < 2; ++p) {                 // transposed ushort8 stores
        const int flat = p * 256 + t;
        const int nn = flat >> 3, cc0 = (flat & 7) * 8;
        ushort8 o;
#pragma unroll
        for (int i = 0; i < 8; ++i) o[i] = f2bf(T[cc0 + i][nn]);
        *(ushort8*)(featT + ((size_t)b * Nn + n0 + nn) * Ck + c0 + cc0) = o;
    }
}

// ---------------------------------------------------------------------------
// bf16 MFMA flash attention, no-max softmax (scores >= 0, <= ~33).
//   featT [B][Nn][Ck] bf16, valB [B][Cv][Nn] bf16, ctx OUT bf16 [B][Nn][Cv]
//
// Round-6: VALU diet + spill kill on the 1-barrier pipeline.
//   * v_cvt_pk_bf16_f32 (inline asm, T12) packs P to bf16: 8 ops replace
//     64 manual-RNE bit ops.
//   * lsum accumulates UNROUNDED exp values (closer to reference softmax).
//   * no reg-held P fragments: PV(s-1) reads all 4 P A-frags from LDS
//     (round-4-verified pattern) -> nothing f32x16-sized lives across the
//     MFMA clusters -> scratch spill (WRITE_SIZE 22MB->16.4MB) gone.
// Kept: swapped QK^T, permlane32_swap pack, gll16 + per-row rotation,
// 1 barrier/tile, counted prologue, batch->XCD grid, setprio, cv-split PV.
// LDS: K 2x32K + V 2x32K + P 2x16K = 163840 B.
// ---------------------------------------------------------------------------
constexpr int LDS_BYTES = 163840;

__global__ __launch_bounds__(512) void attn_mfma(const ushort* __restrict__ featT,
                                                 const ushort* __restrict__ valB,
                                                 ushort* __restrict__ ctx)
{
    extern __shared__ __align__(16) char lds[];
    char* ldsK = lds;              // [buf][64 rows][512 B]  (rotated image)
    char* ldsV = lds + 65536;      // [buf][256 rows][128 B] (rotated image)
    char* ldsP = lds + 131072;     // [buf][ig 4][jb 4][hl 2][32 lanes x 16 B]

    const int b   = blockIdx.x;                  // batch -> XCD affinity
    const int i0  = blockIdx.y * 128;
    const int t   = threadIdx.x;
    const int w   = t >> 6;
    const int L   = t & 63;
    const int l31 = L & 31, hl = L >> 5;
    const int ig  = w >> 1;                      // i-group 0..3 (32 rows each)
    const int ch  = w & 1;                       // j-half (QK) / cv-half (PV)
    const int jsel = ch * 32;

    // read-side rotation bases (verified rounds 3-5)
    const int rbK  = hl * 16 + (((jsel + l31) << 4) & 511);
    const int rotV = (l31 << 4) & 127;

    const ushort* F = featT + (size_t)b * Nn * Ck;
    const ushort* V = valB  + (size_t)b * Cv * Nn;
    const char*   Vg = (const char*)V;

    constexpr float CEXP = 0.09016844005556021f;  // log2(e)/16
    constexpr int NT = Nn / 64;                   // 64 j-tiles

#define STAGE_K(J0, BUF) do {                                                  \
        const char* Kg_ = (const char*)(F + (size_t)(J0) * Ck);                \
        char* Kd_ = ldsK + (BUF) * 32768;                                      \
        _Pragma("unroll")                                                      \
        for (int p_ = 0; p_ < 4; ++p_) {                                       \
            const int c_ = w * 4 + p_;                                         \
            const int o_ = c_ * 1024 + L * 16;                                 \
            const int rK_ = o_ >> 9;                                           \
            gll16(Kg_ + rK_ * 512 + ((o_ - rK_ * 16) & 511), Kd_ + c_ * 1024); \
        }                                                                      \
    } while (0)

#define STAGE_V(J0, BUF) do {                                                  \
        char* Vd_ = ldsV + (BUF) * 32768;                                      \
        _Pragma("unroll")                                                      \
        for (int p_ = 0; p_ < 4; ++p_) {                                       \
            const int c_ = w * 4 + p_;                                         \
            const int o_ = c_ * 1024 + L * 16;                                 \
            const int rV_ = o_ >> 7;                                           \
            gll16(Vg + (size_t)rV_ * (Nn * 2) + (size_t)(J0) * 2               \
                     + ((o_ - rV_ * 16) & 127), Vd_ + c_ * 1024);              \
        }                                                                      \
    } while (0)

    // prologue: K(0) staged; Q fragments; drain + align all waves
    STAGE_K(0, 0);
    short8 Qf[16];
    {
        const ushort* qp = F + ((size_t)(i0 + ig * 32 + l31)) * Ck + hl * 8;
#pragma unroll
        for (int kc = 0; kc < 16; ++kc)
            Qf[kc] = *(const short8*)(qp + kc * 16);
    }
    asm volatile("s_waitcnt vmcnt(0)" ::: "memory");
    __builtin_amdgcn_s_barrier();

    f32x16 Oacc[4];
#pragma unroll
    for (int c = 0; c < 4; ++c)
#pragma unroll
        for (int r = 0; r < 16; ++r) Oacc[c][r] = 0.f;
    float lsum = 0.f;

    int cur = 0;
    for (int s = 0; s < NT; ++s) {
        // stage K(s+1) and V(s) — consumed next iteration
        const int jn = (s + 1 < NT ? s + 1 : NT - 1) * 64;
        STAGE_K(jn, cur ^ 1);
        STAGE_V((size_t)s * 64, cur);

        // ---- QK(s): S^T[j][i] from K[cur] ----
        const char* Kr = ldsK + cur * 32768 + (jsel + l31) * 512;
        f32x16 Sa, Sb;
#pragma unroll
        for (int r = 0; r < 16; ++r) { Sa[r] = 0.f; Sb[r] = 0.f; }
        __builtin_amdgcn_s_setprio(1);
#pragma unroll
        for (int kc = 0; kc < 8; ++kc) {
            const short8 K0 = *(const short8*)(Kr + ((kc * 64      + rbK) & 511));
            const short8 K1 = *(const short8*)(Kr + ((kc * 64 + 32 + rbK) & 511));
            Sa = __builtin_amdgcn_mfma_f32_32x32x16_bf16(K0, Qf[2 * kc],     Sa, 0, 0, 0);
            Sb = __builtin_amdgcn_mfma_f32_32x32x16_bf16(K1, Qf[2 * kc + 1], Sb, 0, 0, 0);
        }
        __builtin_amdgcn_s_setprio(0);

        // ---- PV(s-1): all 4 P frags + V from buf cur^1 ----
        if (s > 0) {
            const char* Vr2 = ldsV + (cur ^ 1) * 32768 + (ch * 128 + l31) * 128;
            const char* Pr  = ldsP + (cur ^ 1) * 16384 + (ig * 8 + hl) * 512 + l31 * 16;
            __builtin_amdgcn_s_setprio(1);
#pragma unroll
            for (int jb = 0; jb < 4; ++jb) {
                const short8 Pa = *(const short8*)(Pr + jb * 1024);
                const int jbyte = jb * 32 + hl * 16;
#pragma unroll
                for (int cvt = 0; cvt < 4; ++cvt) {
                    const short8 Vf = *(const short8*)(Vr2 + cvt * 4096
                                         + ((jbyte + rotV) & 127));
                    Oacc[cvt] = __builtin_amdgcn_mfma_f32_32x32x16_bf16(
                        Pa, Vf, Oacc[cvt], 0, 0, 0);
                }
            }
            __builtin_amdgcn_s_setprio(0);
        }

        // ---- softmax: exp + cvt_pk (hw RNE) + UNROUNDED lsum ----
        unsigned pw[8];
#pragma unroll
        for (int r2 = 0; r2 < 8; ++r2) {
            const float p0 = exp2f((Sa[2 * r2]     + Sb[2 * r2])     * CEXP);
            const float p1 = exp2f((Sa[2 * r2 + 1] + Sb[2 * r2 + 1]) * CEXP);
            lsum += p0 + p1;
            unsigned pk;
            asm("v_cvt_pk_bf16_f32 %0, %1, %2" : "=v"(pk) : "v"(p0), "v"(p1));
            pw[r2] = pk;
        }
        {
            char* Pw = ldsP + cur * 16384
                       + ((ig * 4 + ch * 2) * 2 + hl) * 512 + l31 * 16;
#pragma unroll
            for (int g = 0; g < 2; ++g) {
                auto s02 = __builtin_amdgcn_permlane32_swap(pw[4 * g + 0], pw[4 * g + 2],
                                                            false, false);
                auto s13 = __builtin_amdgcn_permlane32_swap(pw[4 * g + 1], pw[4 * g + 3],
                                                            false, false);
                union { unsigned u[4]; short8 s; } pu;
                pu.u[0] = s02[0]; pu.u[1] = s13[0]; pu.u[2] = s02[1]; pu.u[3] = s13[1];
                *(short8*)(Pw + g * 1024) = pu.s;
            }
        }

        // drain MY glls + ds ops, then align: everyone's staging visible
        asm volatile("s_waitcnt vmcnt(0) lgkmcnt(0)" ::: "memory");
        __builtin_amdgcn_s_barrier();
        cur ^= 1;
    }
#undef STAGE_K
#undef STAGE_V

    // ---- epilogue PV(NT-1): P[cur^1], V[cur^1] ----
    {
        const char* Vr2 = ldsV + (cur ^ 1) * 32768 + (ch * 128 + l31) * 128;
        const char* Pr  = ldsP + (cur ^ 1) * 16384 + (ig * 8 + hl) * 512 + l31 * 16;
#pragma unroll
        for (int jb = 0; jb < 4; ++jb) {
            const short8 Pa = *(const short8*)(Pr + jb * 1024);
            const int jbyte = jb * 32 + hl * 16;
#pragma unroll
            for (int cvt = 0; cvt < 4; ++cvt) {
                const short8 Vf = *(const short8*)(Vr2 + cvt * 4096
                                     + ((jbyte + rotV) & 127));
                Oacc[cvt] = __builtin_amdgcn_mfma_f32_32x32x16_bf16(
                    Pa, Vf, Oacc[cvt], 0, 0, 0);
            }
        }
    }

    // ---- l merge (hl in-reg, ch via LDS; Lr aliases dead P buf 0) ----
    {
        unsigned a = __float_as_uint(lsum), bcopy = a;
        auto sw = __builtin_amdgcn_permlane32_swap(a, bcopy, false, false);
        lsum = __uint_as_float(sw[0]) + __uint_as_float(sw[1]);
    }
    float* Lr = (float*)ldsP;          // P buf0 dead (epilogue reads buf1)
    Lr[(ig * 2 + ch) * 32 + l31] = lsum;
    asm volatile("s_waitcnt lgkmcnt(0)" ::: "memory");
    __builtin_amdgcn_s_barrier();

    ushort* Cb = ctx + ((size_t)b * Nn + i0 + ig * 32) * Cv + ch * 128;
#pragma unroll
    for (int r = 0; r < 16; ++r) {
        const int row = (r & 3) + 8 * (r >> 2) + 4 * hl;
        const float lt = Lr[(ig * 2) * 32 + row] + Lr[(ig * 2 + 1) * 32 + row];
        const float linv = 1.f / lt;
        ushort* cp = Cb + (size_t)row * Cv + l31;
#pragma unroll
        for (int c4 = 0; c4 < 4; ++c4)
            cp[c4 * 32] = f2bf(Oacc[c4][r] * linv);
    }
}

// ---------------------------------------------------------------------------
// Final 1x1 conv GEMM (unchanged structure):
//   out[b][m][n] = sum_k Wb[m][k] * XT[b][n][k] + bias[m]
// ---------------------------------------------------------------------------
template <int K>
__global__ __launch_bounds__(256) void gemm_bf(const ushort* __restrict__ XT,
                                               const ushort* __restrict__ Wb,
                                               const float*  __restrict__ bias,
                                               float* __restrict__ out,
                                               int M)
{
    const int b  = blockIdx.z;
    const int m0 = blockIdx.y * 128;
    const int n0 = blockIdx.x * 128;
    const int t  = threadIdx.x;
    const int w  = t >> 6, L = t & 63;
    const int l31 = L & 31, hl = L >> 5;
    const int wm = (w >> 1) * 64, wn = (w & 1) * 64;

    __shared__ __align__(16) short As[128][72];   // [m][k]
    __shared__ __align__(16) short Bs[128][72];   // [n][k]

    const ushort* Xb = XT + (size_t)b * Nn * K;

    f32x16 acc[2][2];
#pragma unroll
    for (int a = 0; a < 2; ++a)
#pragma unroll
        for (int bb = 0; bb < 2; ++bb)
#pragma unroll
            for (int r = 0; r < 16; ++r) acc[a][bb][r] = 0.f;

    for (int k0 = 0; k0 < K; k0 += 64) {
        __syncthreads();
#pragma unroll
        for (int p = 0; p < 4; ++p) {            // stage 128x64 A and B tiles
            const int e   = p * 256 + t;
            const int row = e >> 3, ko = (e & 7) * 8;
            *(short8*)&As[row][ko] =
                *(const short8*)(Wb + (size_t)(m0 + row) * K + k0 + ko);
            *(short8*)&Bs[row][ko] =
                *(const short8*)(Xb + (size_t)(n0 + row) * K + k0 + ko);
        }
        __syncthreads();
#pragma unroll
        for (int kc = 0; kc < 4; ++kc) {
            short8 Af[2], Bf[2];
#pragma unroll
            for (int a = 0; a < 2; ++a)
                Af[a] = *(const short8*)&As[wm + a * 32 + l31][kc * 16 + hl * 8];
#pragma unroll
            for (int bb = 0; bb < 2; ++bb)
                Bf[bb] = *(const short8*)&Bs[wn + bb * 32 + l31][kc * 16 + hl * 8];
#pragma unroll
            for (int a = 0; a < 2; ++a)
#pragma unroll
                for (int bb = 0; bb < 2; ++bb)
                    acc[a][bb] = __builtin_amdgcn_mfma_f32_32x32x16_bf16(
                        Af[a], Bf[bb], acc[a][bb], 0, 0, 0);
        }
    }

    // epilogue: D row=(r&3)+8*(r>>2)+4*hl, col=l31
#pragma unroll
    for (int a = 0; a < 2; ++a)
#pragma unroll
        for (int r = 0; r < 16; ++r) {
            const int row = (r & 3) + 8 * (r >> 2) + 4 * hl;
            const int o   = m0 + wm + a * 32 + row;
            const float bv = bias[o];
            const size_t base = ((size_t)b * M + o) * Nn + n0 + wn + l31;
#pragma unroll
            for (int bb = 0; bb < 2; ++bb)
                out[base + bb * 32] = acc[a][bb][r] + bv;
        }
}

// ---------------------------------------------------------------------------
extern "C" void kernel_launch(void* const* d_in, const int* in_sizes, int n_in,
                              void* d_out, int out_size, void* d_ws, size_t ws_size,
                              hipStream_t stream)
{
    const float* x     = (const float*)d_in[0];
    const float* Wk    = (const float*)d_in[1];
    const float* bk    = (const float*)d_in[2];
    const float* gamma = (const float*)d_in[3];
    const float* beta  = (const float*)d_in[4];
    const float* Wv    = (const float*)d_in[5];
    const float* bv    = (const float*)d_in[6];
    const float* Ww    = (const float*)d_in[7];
    const float* bw    = (const float*)d_in[8];

    float* out = (float*)d_out;
    float* f1  = out + F1_OFF;
    float* f2  = out + F2_OFF;
    float* val = out + VAL_OFF;

    // workspace packing (51.1 MB), with aliasing over dead xT:
    //   xT    : [0 .. 16,777,216) ushorts   live steps 2-3
    //   featT : alias xT[0 .. 8,388,608)    live steps 5-6
    //   ctxb  : alias xT[8,388,608 .. )     live steps 6-7
    ushort* xT    = (ushort*)d_ws;                       // [B][Nn][Cin]
    ushort* featT = xT;                                  // [B][Nn][Ck]
    ushort* ctxb  = xT + (size_t)8388608;                // [B][Nn][Cv]
    ushort* valB  = xT + (size_t)16777216;               // [B][Cv][Nn]
    ushort* Wkb   = valB + (size_t)8388608;
    ushort* Wvb   = Wkb + 131072;
    ushort* Wwb   = Wvb + 131072;
    float*  ss    = (float*)(Wwb + 131072);              // 512 floats

    // one-time: allow 160 KB dynamic LDS for the attention kernel
    static bool attn_attr_set = false;
    if (!attn_attr_set) {
        (void)hipFuncSetAttribute((const void*)attn_mfma,
                                  hipFuncAttributeMaxDynamicSharedMemorySize,
                                  LDS_BYTES);
        attn_attr_set = true;
    }

    // 1) weights -> bf16
    cast_w<<<192, 256, 0, stream>>>(Wk, Wv, Ww, Wkb, Wvb, Wwb);
    // 2) x -> xT bf16 [B][Nn][Cin]
    transpose_c<<<dim3(Nn / 64, Cin / 64, Bn), 256, 0, stream>>>(x, xT, Cin);
    // 3) fused: qk = Wk*x + bk (fp32) AND value = Wv*x + bv (fp32 + bf16)
    gemm_qv<<<dim3(Nn / 128, Ck / 128, Bn), 256, 0, stream>>>(
        xT, Wkb, Wvb, bk, bv, f1, val, valB);
    // 4) BN stats
    bn_stats<<<Ck, 256, 0, stream>>>(f1, gamma, beta, ss);
    // 5) fused: feat = relu(norm(qk)) -> f1, f2 AND featT bf16 (xT dead)
    bn_relu_t<<<dim3(Nn / 64, Ck / 64, Bn), 256, 0, stream>>>(
        f1, ss, f1, f2, featT);
    // 6) flash attention -> ctx bf16 [B][Nn][Cv]
    attn_mfma<<<dim3(Bn, Nn / 128), 512, LDS_BYTES, stream>>>(featT, valB, ctxb);
    // 7) out = Ww*ctx + bw
    gemm_bf<256><<<dim3(Nn / 128, Co / 128, Bn), 256, 0, stream>>>(
        ctxb, Wwb, bw, out, Co);
}